// Round 1
// baseline (468.297 us; speedup 1.0000x reference)
//
#include <hip/hip_runtime.h>
#include <hip/hip_bf16.h>
#include <math.h>

#define NUM_CLASSES 21
#define NCM1        20      // classes minus background
#define TOP_K       200
#define K_CAND      400
#define NMS_THRESH  0.45f
#define CONF_THRESH 0.01f
#define VAR0        0.1f
#define VAR1        0.2f
#define P           24564
#define BS          16

#define MASK_W      7       // ceil(400/64)
#define CAND_CAP    1024

typedef unsigned long long u64;
typedef unsigned int u32;

// ---------------- K0: transpose conf [B,P,21] -> confT [B,20,P] ----------------
__global__ __launch_bounds__(256) void k_transpose(const float* __restrict__ conf,
                                                   float* __restrict__ confT) {
    int gid = blockIdx.x * 256 + threadIdx.x;       // over B*P
    if (gid >= BS * P) return;
    int b = gid / P, p = gid - b * P;
    const float* src = conf + (size_t)gid * NUM_CLASSES;
#pragma unroll
    for (int c = 1; c < NUM_CLASSES; ++c)
        confT[((size_t)(b * NCM1 + (c - 1))) * P + p] = src[c];
}

// ---------------- K1: per-(image,class) top-400 + NMS ----------------
__global__ __launch_bounds__(256) void k_nms(
    const float* __restrict__ loc, const float* __restrict__ priors,
    const float* __restrict__ conf, const float* __restrict__ confT, int use_t,
    float* __restrict__ dets, int* __restrict__ counts) {

    const int tid = threadIdx.x;
    const int task = blockIdx.x;            // 0..319
    const int b = task / NCM1, c0 = task - b * NCM1;

    __shared__ u32 hist[4][256];
    __shared__ u32 suf[256];
    __shared__ u32 s_cut, s_k, s_ncand;
    __shared__ u64 cand[CAND_CAP];
    __shared__ float sx1[K_CAND], sy1[K_CAND], sx2[K_CAND], sy2[K_CAND];
    __shared__ float sar[K_CAND], ssc[K_CAND];
    __shared__ unsigned char sval[K_CAND];
    __shared__ u64 iou_mask[K_CAND][MASK_W];
    __shared__ u64 kept_w[MASK_W];
    __shared__ int s_cnt;

    const float* sp;
    long sstride;
    if (use_t) { sp = confT + (size_t)task * P; sstride = 1; }
    else       { sp = conf + (size_t)b * P * NUM_CLASSES + (c0 + 1); sstride = NUM_CLASSES; }

    // ---- 4-round MSB radix select: V = bits of the 400th-largest score ----
    u32 prefix = 0;
    u32 k = K_CAND;
    const int wv = tid >> 6;
    for (int round = 0; round < 4; ++round) {
        hist[0][tid] = 0; hist[1][tid] = 0; hist[2][tid] = 0; hist[3][tid] = 0;
        __syncthreads();
        const int msb = 8 * round;
        const int dsh = 24 - 8 * round;
        for (int p = tid; p < P; p += 256) {
            u32 u = __float_as_uint(sp[(size_t)p * sstride]);
            bool match = (round == 0) || ((u >> (32 - msb)) == prefix);
            if (match) atomicAdd(&hist[wv][(u >> dsh) & 0xFF], 1u);
        }
        __syncthreads();
        suf[tid] = hist[0][tid] + hist[1][tid] + hist[2][tid] + hist[3][tid];
        __syncthreads();
        for (int off = 1; off < 256; off <<= 1) {
            u32 v = suf[tid] + ((tid + off < 256) ? suf[tid + off] : 0u);
            __syncthreads();
            suf[tid] = v;
            __syncthreads();
        }
        if (suf[tid] >= k && (tid == 255 || suf[tid + 1] < k)) {
            s_cut = (u32)tid;
            s_k = k - ((tid == 255) ? 0u : suf[tid + 1]);
        }
        __syncthreads();
        prefix = (prefix << 8) | s_cut;
        k = s_k;
        __syncthreads();
    }
    const u32 V = prefix;

    // ---- collect all score-bits >= V as composite keys ----
    if (tid == 0) s_ncand = 0;
    __syncthreads();
    for (int p = tid; p < P; p += 256) {
        u32 u = __float_as_uint(sp[(size_t)p * sstride]);
        if (u >= V) {
            u32 pos = atomicAdd(&s_ncand, 1u);
            if (pos < CAND_CAP) cand[pos] = ((u64)u << 32) | (u32)(~(u32)p);
        }
    }
    __syncthreads();
    const u32 ncand = min(s_ncand, (u32)CAND_CAP);
    for (u32 i = ncand + tid; i < CAND_CAP; i += 256) cand[i] = 0ull;
    __syncthreads();

    // ---- bitonic sort CAND_CAP descending (score desc, idx asc) ----
    for (u32 ksz = 2; ksz <= CAND_CAP; ksz <<= 1) {
        for (u32 j = ksz >> 1; j > 0; j >>= 1) {
            for (u32 t = tid; t < CAND_CAP / 2; t += 256) {
                u32 i = 2 * t - (t & (j - 1));
                u32 ixj = i | j;
                u64 a = cand[i], c = cand[ixj];
                bool up = ((i & ksz) == 0);
                if (up ? (a < c) : (a > c)) { cand[i] = c; cand[ixj] = a; }
            }
            __syncthreads();
        }
    }

    // ---- decode top-400 candidate boxes (reference op order) ----
    for (int r = tid; r < K_CAND; r += 256) {
        if ((u32)r < ncand) {
            u64 key = cand[r];
            u32 idx = ~(u32)key;
            float sc = __uint_as_float((u32)(key >> 32));
            float4 lc = ((const float4*)loc)[(size_t)b * P + idx];
            float4 pr = ((const float4*)priors)[idx];
            float cx = pr.x + lc.x * VAR0 * pr.z;
            float cy = pr.y + lc.y * VAR0 * pr.w;
            float w  = pr.z * expf(lc.z * VAR1);
            float h  = pr.w * expf(lc.w * VAR1);
            float x1 = cx - w * 0.5f, y1 = cy - h * 0.5f;
            float x2 = x1 + w, y2 = y1 + h;
            sx1[r] = x1; sy1[r] = y1; sx2[r] = x2; sy2[r] = y2;
            sar[r] = (x2 - x1) * (y2 - y1);
            ssc[r] = sc;
            sval[r] = (sc > CONF_THRESH) ? 1 : 0;
        } else {
            sx1[r] = 0; sy1[r] = 0; sx2[r] = 0; sy2[r] = 0;
            sar[r] = 0; ssc[r] = 0; sval[r] = 0;
        }
    }
    __syncthreads();

    // ---- 400x400 IoU>thresh bitmask ----
    for (int t = tid; t < K_CAND * MASK_W; t += 256) {
        int i = t / MASK_W, w = t - i * MASK_W;
        float ix1 = sx1[i], iy1 = sy1[i], ix2 = sx2[i], iy2 = sy2[i], iar = sar[i];
        u64 m = 0;
        int j0 = w * 64;
        int jend = j0 + 64; if (jend > K_CAND) jend = K_CAND;
        for (int j = j0; j < jend; ++j) {
            float xx1 = fmaxf(ix1, sx1[j]);
            float yy1 = fmaxf(iy1, sy1[j]);
            float xx2 = fminf(ix2, sx2[j]);
            float yy2 = fminf(iy2, sy2[j]);
            float iw = fmaxf(xx2 - xx1, 0.0f);
            float ih = fmaxf(yy2 - yy1, 0.0f);
            float inter = iw * ih;
            float uni = iar + sar[j] - inter;
            float iou = inter / fmaxf(uni, 1e-9f);
            if (iou > NMS_THRESH) m |= (1ull << (j - j0));
        }
        iou_mask[i][w] = m;
    }
    __syncthreads();

    // ---- greedy NMS, single wave; lane l holds kept-word l ----
    if (tid < 64) {
        int l = tid;
        u64 kw = 0;
        int cnt = 0;
        for (int i = 0; i < K_CAND; ++i) {
            if (!sval[i]) break;                       // scores desc => valid is a prefix
            u64 mm = (l < MASK_W) ? iou_mask[i][l] : 0ull;
            bool sup = __any((kw & mm) != 0ull);
            if (!sup && cnt < TOP_K) {
                if (l == (i >> 6)) kw |= (1ull << (i & 63));
                ++cnt;
                if (cnt >= TOP_K) break;
            }
        }
        if (l < MASK_W) kept_w[l] = kw;
        if (l == 0) s_cnt = cnt;
    }
    __syncthreads();

    // ---- compact kept (score order == index order) into dets ----
    for (int i = tid; i < K_CAND; i += 256) {
        u64 w = kept_w[i >> 6];
        if ((w >> (i & 63)) & 1ull) {
            int rank = 0;
            for (int q = 0; q < (i >> 6); ++q) rank += __popcll(kept_w[q]);
            rank += __popcll(w & ((1ull << (i & 63)) - 1ull));
            float* dst = dets + ((size_t)task * TOP_K + rank) * 6;
            dst[0] = sx1[i]; dst[1] = sy1[i]; dst[2] = sx2[i]; dst[3] = sy2[i];
            dst[4] = ssc[i]; dst[5] = (float)(c0 + 1);
        }
    }
    if (tid == 0) counts[task] = s_cnt;
}

// ---------------- K2: per-image global sort of 4000 slots -> output ----------------
#define NSLOT (NCM1 * TOP_K)     // 4000
#define NSORT 4096
#define OUTR  (NUM_CLASSES * TOP_K)  // 4200

__global__ __launch_bounds__(1024) void k_final(const float* __restrict__ dets,
                                                const int* __restrict__ counts,
                                                float* __restrict__ out) {
    const int b = blockIdx.x, tid = threadIdx.x;
    __shared__ u64 key[NSORT];

    for (int f = tid; f < NSORT; f += 1024) {
        u64 kk = 0;
        if (f < NSLOT) {
            int c0 = f / TOP_K, slot = f - c0 * TOP_K;
            if (slot < counts[b * NCM1 + c0]) {
                float sc = dets[((size_t)(b * NCM1 + c0) * TOP_K + slot) * 6 + 4];
                kk = ((u64)__float_as_uint(sc) << 32) | (u32)(~(u32)f);
            }
        }
        key[f] = kk;
    }
    __syncthreads();

    for (u32 ksz = 2; ksz <= NSORT; ksz <<= 1) {
        for (u32 j = ksz >> 1; j > 0; j >>= 1) {
            for (u32 t = tid; t < NSORT / 2; t += 1024) {
                u32 i = 2 * t - (t & (j - 1));
                u32 ixj = i | j;
                u64 a = key[i], c = key[ixj];
                bool up = ((i & ksz) == 0);
                if (up ? (a < c) : (a > c)) { key[i] = c; key[ixj] = a; }
            }
            __syncthreads();
        }
    }

    for (int r = tid; r < OUTR; r += 1024) {
        float o0 = 0, o1 = 0, o2 = 0, o3 = 0, o4 = 0, o5 = 0;
        if (r < NSORT) {
            u64 kk = key[r];
            if (kk) {
                int f = (int)(~(u32)kk);
                int c0 = f / TOP_K, slot = f - c0 * TOP_K;
                const float* src = dets + ((size_t)(b * NCM1 + c0) * TOP_K + slot) * 6;
                o0 = src[0]; o1 = src[1]; o2 = src[2];
                o3 = src[3]; o4 = src[4]; o5 = src[5];
            }
        }
        float* dst = out + ((size_t)b * OUTR + r) * 6;
        dst[0] = o0; dst[1] = o1; dst[2] = o2; dst[3] = o3; dst[4] = o4; dst[5] = o5;
    }
}

extern "C" void kernel_launch(void* const* d_in, const int* in_sizes, int n_in,
                              void* d_out, int out_size, void* d_ws, size_t ws_size,
                              hipStream_t stream) {
    const float* loc    = (const float*)d_in[0];
    const float* conf   = (const float*)d_in[1];
    const float* priors = (const float*)d_in[2];
    float* out = (float*)d_out;

    size_t off = 0;
    float* dets = (float*)((char*)d_ws + off);
    off += (size_t)BS * NCM1 * TOP_K * 6 * sizeof(float);          // 1,536,000
    int* counts = (int*)((char*)d_ws + off);
    off += (size_t)BS * NCM1 * sizeof(int);
    off = (off + 255) & ~(size_t)255;
    float* confT = (float*)((char*)d_ws + off);
    size_t need_T = off + (size_t)BS * NCM1 * P * sizeof(float);   // ~32.98 MB total
    int use_t = (ws_size >= need_T) ? 1 : 0;

    if (use_t) {
        int total = BS * P;
        k_transpose<<<(total + 255) / 256, 256, 0, stream>>>(conf, confT);
    }
    k_nms<<<BS * NCM1, 256, 0, stream>>>(loc, priors, conf, confT, use_t, dets, counts);
    k_final<<<BS, 1024, 0, stream>>>(dets, counts, out);
}